// Round 1
// baseline (526.353 us; speedup 1.0000x reference)
//
#include <hip/hip_runtime.h>
#include <hip/hip_bf16.h>
#include <cstdint>
#include <cstddef>

typedef __bf16 bf16;
typedef bf16 bf16x4 __attribute__((ext_vector_type(4)));
typedef bf16 bf16x8 __attribute__((ext_vector_type(8)));
typedef float floatx4 __attribute__((ext_vector_type(4)));

#define MFMA16(a, b, c) __builtin_amdgcn_mfma_f32_16x16x32_bf16((a), (b), (c), 0, 0, 0)

// ---------------------------------------------------------------------------
// async global->LDS, 16B per lane. LDS base must be wave-uniform; HW writes
// base + lane*16.
// ---------------------------------------------------------------------------
__device__ __forceinline__ void async16(const void* g, void* l) {
    __builtin_amdgcn_global_load_lds((const __attribute__((address_space(1))) void*)g,
                                     (__attribute__((address_space(3))) void*)l,
                                     16, 0, 0);
}

// stage a 64x64 bf16 tile (global row stride ldg elems) into LDS (row stride 64)
// 8 instructions total across 4 waves (2 per wave); each instr covers 8 rows.
__device__ __forceinline__ void stage64(const bf16* g0, int ldg, bf16* lds, int wave, int lane) {
#pragma unroll
    for (int i = 0; i < 2; ++i) {
        int r0 = wave * 16 + i * 8;                       // wave-uniform
        async16(g0 + (size_t)(r0 + (lane >> 3)) * ldg + (lane & 7) * 8,
                lds + r0 * 64);
    }
}

// ---------------------------------------------------------------------------
// fp32 -> bf16 convert
// ---------------------------------------------------------------------------
__global__ __launch_bounds__(256) void cvt_bf16(const float* __restrict__ in,
                                                bf16* __restrict__ out, int n) {
    int i = (blockIdx.x * 256 + threadIdx.x) * 4;
    if (i < n) {
        float4 v = *(const float4*)(in + i);
        bf16x4 o = {(bf16)v.x, (bf16)v.y, (bf16)v.z, (bf16)v.w};
        *(bf16x4*)(out + i) = o;
    }
}

// ---------------------------------------------------------------------------
// Generic bf16 GEMM: C[M,N] = A[M,K] * B[N,K]^T, 128x128 tile, BK=32.
// EPI 0: store bf16 to Cb
// EPI 1: v = acc + res[row,col] (fp32); store fp32 to Cf AND bf16 to Cb
// EPI 2: v = relu(acc + bias[col]); store bf16 to Cb
// EPI 3: v = acc + bias[col] + Cf[row,col]; store fp32 to Cf
// ---------------------------------------------------------------------------
template <int EPI>
__global__ __launch_bounds__(256) void gemm128(const bf16* __restrict__ A, int lda,
                                               const bf16* __restrict__ B, int ldb, int K,
                                               float* __restrict__ Cf, bf16* __restrict__ Cb,
                                               int ldc, const float* __restrict__ bias,
                                               const float* __restrict__ res) {
    __shared__ __align__(16) bf16 As[128 * 32];
    __shared__ __align__(16) bf16 Bs[128 * 32];
    const int tid = threadIdx.x, wave = tid >> 6, lane = tid & 63;
    const int m0 = blockIdx.y * 128, n0 = blockIdx.x * 128;
    const int wm = (wave >> 1) * 64, wn = (wave & 1) * 64;
    const int col = lane & 15, quad = lane >> 4;

    floatx4 acc[4][4];
#pragma unroll
    for (int mi = 0; mi < 4; ++mi)
#pragma unroll
        for (int ni = 0; ni < 4; ++ni) acc[mi][ni] = (floatx4){0.f, 0.f, 0.f, 0.f};

    for (int k0 = 0; k0 < K; k0 += 32) {
        __syncthreads();  // prior ds_reads of As/Bs complete before overwrite
#pragma unroll
        for (int i = 0; i < 2; ++i) {
            int r0 = wave * 32 + i * 16;  // wave-uniform; instr covers 16 rows of 64B
            async16(A + (size_t)(m0 + r0 + (lane >> 2)) * lda + k0 + (lane & 3) * 8,
                    As + r0 * 32);
            async16(B + (size_t)(n0 + r0 + (lane >> 2)) * ldb + k0 + (lane & 3) * 8,
                    Bs + r0 * 32);
        }
        __syncthreads();  // drains vmcnt for global_load_lds

        bf16x8 af[4], bfr[4];
#pragma unroll
        for (int mi = 0; mi < 4; ++mi)
            af[mi] = *(const bf16x8*)&As[(wm + mi * 16 + col) * 32 + quad * 8];
#pragma unroll
        for (int ni = 0; ni < 4; ++ni)
            bfr[ni] = *(const bf16x8*)&Bs[(wn + ni * 16 + col) * 32 + quad * 8];
#pragma unroll
        for (int mi = 0; mi < 4; ++mi)
#pragma unroll
            for (int ni = 0; ni < 4; ++ni)
                acc[mi][ni] = MFMA16(af[mi], bfr[ni], acc[mi][ni]);
    }

#pragma unroll
    for (int mi = 0; mi < 4; ++mi)
#pragma unroll
        for (int ni = 0; ni < 4; ++ni)
#pragma unroll
            for (int r = 0; r < 4; ++r) {
                int row = m0 + wm + mi * 16 + quad * 4 + r;
                int cc = n0 + wn + ni * 16 + col;
                size_t idx = (size_t)row * ldc + cc;
                float v = acc[mi][ni][r];
                if constexpr (EPI == 0) {
                    Cb[idx] = (bf16)v;
                } else if constexpr (EPI == 1) {
                    v += res[idx];
                    Cf[idx] = v;
                    Cb[idx] = (bf16)v;
                } else if constexpr (EPI == 2) {
                    v += bias[cc];
                    v = fmaxf(v, 0.f);
                    Cb[idx] = (bf16)v;
                } else {
                    v += bias[cc] + Cf[idx];
                    Cf[idx] = v;
                }
            }
}

// ---------------------------------------------------------------------------
// Transpose V: qkv[b*2048+c][2048 + a*64 + h] -> vt[(bh*64+h)][c]  (bf16)
// grid (32 ctiles, 32 bh)
// ---------------------------------------------------------------------------
__global__ __launch_bounds__(256) void transpose_v(const bf16* __restrict__ qkv,
                                                   bf16* __restrict__ vt) {
    __shared__ bf16 t[64][65];
    const int bh = blockIdx.y, ct = blockIdx.x;
    const int b = bh >> 4, a = bh & 15;
    for (int idx = threadIdx.x; idx < 4096; idx += 256) {
        int c = idx >> 6, h = idx & 63;
        t[h][c] = qkv[(size_t)(b * 2048 + ct * 64 + c) * 3072 + 2048 + a * 64 + h];
    }
    __syncthreads();
    for (int idx = threadIdx.x; idx < 4096; idx += 256) {
        int h = idx >> 6, c = idx & 63;
        vt[(size_t)(bh * 64 + h) * 2048 + ct * 64 + c] = t[h][c];
    }
}

// ---------------------------------------------------------------------------
// Attention pass 1: per-row softmax stats. Row c is normalized over C <= c.
// S[c][C] = (k_c . q_C) / 8.  grid (32 ctiles, 32 bh), 4 waves, wave w owns
// 16-row c-strip.
// ---------------------------------------------------------------------------
__global__ __launch_bounds__(256) void attn_stats(const bf16* __restrict__ qkv,
                                                  float* __restrict__ mstat,
                                                  float* __restrict__ lstat) {
    __shared__ __align__(16) bf16 Kt[64 * 64];
    __shared__ __align__(16) bf16 Qt[64 * 64];
    const int bh = blockIdx.y, ct = blockIdx.x;
    const int b = bh >> 4, a = bh & 15;
    const int tid = threadIdx.x, wave = tid >> 6, lane = tid & 63;
    const int col = lane & 15, quad = lane >> 4;
    const bf16* base = qkv + (size_t)b * 2048 * 3072;

    stage64(base + (size_t)ct * 64 * 3072 + 1024 + a * 64, 3072, Kt, wave, lane);

    float mrun[4], lrun[4];
#pragma unroll
    for (int r = 0; r < 4; ++r) { mrun[r] = -3e38f; lrun[r] = 0.f; }

    for (int Ct = 0; Ct <= ct; ++Ct) {
        if (Ct) __syncthreads();  // everyone done reading previous Qt
        stage64(base + (size_t)Ct * 64 * 3072 + a * 64, 3072, Qt, wave, lane);
        __syncthreads();

        bf16x8 a0 = *(const bf16x8*)&Kt[(wave * 16 + col) * 64 + quad * 8];
        bf16x8 a1 = *(const bf16x8*)&Kt[(wave * 16 + col) * 64 + 32 + quad * 8];

        float s[4][4];
#pragma unroll
        for (int nt = 0; nt < 4; ++nt) {
            bf16x8 b0 = *(const bf16x8*)&Qt[(nt * 16 + col) * 64 + quad * 8];
            bf16x8 b1 = *(const bf16x8*)&Qt[(nt * 16 + col) * 64 + 32 + quad * 8];
            floatx4 acc = (floatx4){0.f, 0.f, 0.f, 0.f};
            acc = MFMA16(a0, b0, acc);
            acc = MFMA16(a1, b1, acc);
#pragma unroll
            for (int r = 0; r < 4; ++r) {
                float v = acc[r] * 0.125f;
                // mask: valid iff global C <= global c
                if (Ct == ct && (nt * 16 + col) > (wave * 16 + quad * 4 + r)) v = -3e38f;
                s[nt][r] = v;
            }
        }
#pragma unroll
        for (int r = 0; r < 4; ++r) {
            float tm = fmaxf(fmaxf(s[0][r], s[1][r]), fmaxf(s[2][r], s[3][r]));
            tm = fmaxf(tm, __shfl_xor(tm, 1));
            tm = fmaxf(tm, __shfl_xor(tm, 2));
            tm = fmaxf(tm, __shfl_xor(tm, 4));
            tm = fmaxf(tm, __shfl_xor(tm, 8));
            float nm = fmaxf(mrun[r], tm);
            float ts = __expf(s[0][r] - nm) + __expf(s[1][r] - nm) +
                       __expf(s[2][r] - nm) + __expf(s[3][r] - nm);
            ts += __shfl_xor(ts, 1);
            ts += __shfl_xor(ts, 2);
            ts += __shfl_xor(ts, 4);
            ts += __shfl_xor(ts, 8);
            lrun[r] = lrun[r] * __expf(mrun[r] - nm) + ts;
            mrun[r] = nm;
        }
    }
    if (col == 0) {
#pragma unroll
        for (int r = 0; r < 4; ++r) {
            int c = ct * 64 + wave * 16 + quad * 4 + r;
            mstat[(size_t)bh * 2048 + c] = mrun[r];
            lstat[(size_t)bh * 2048 + c] = lrun[r];
        }
    }
}

// ---------------------------------------------------------------------------
// Attention pass 2: z[C][h] = sum_{c>=C} P[c][C] * v[c][h],
// P[c][C] = exp(S[c][C]/8 - m_c) / l_c.  grid (32 Ctiles, 32 bh).
// Wave w: generates P for c-strip w, accumulates z for h-strip w.
// ---------------------------------------------------------------------------
__global__ __launch_bounds__(256) void attn_av(const bf16* __restrict__ qkv,
                                               const bf16* __restrict__ vt,
                                               const float* __restrict__ mstat,
                                               const float* __restrict__ lstat,
                                               bf16* __restrict__ zb) {
    __shared__ __align__(16) bf16 Qt[64 * 64];
    __shared__ __align__(16) bf16 Kt[64 * 64];
    __shared__ __align__(16) bf16 Vt[64 * 64];   // V^T tile: rows h, cols c
    __shared__ __align__(16) bf16 Pt[64 * 72];   // P^T tile: rows C, cols c (pad 72)
    const int bh = blockIdx.y, Ctile = blockIdx.x;
    const int b = bh >> 4, a = bh & 15;
    const int tid = threadIdx.x, wave = tid >> 6, lane = tid & 63;
    const int col = lane & 15, quad = lane >> 4;
    const bf16* base = qkv + (size_t)b * 2048 * 3072;

    stage64(base + (size_t)Ctile * 64 * 3072 + a * 64, 3072, Qt, wave, lane);

    floatx4 zacc[4];
#pragma unroll
    for (int mi = 0; mi < 4; ++mi) zacc[mi] = (floatx4){0.f, 0.f, 0.f, 0.f};

    for (int ct = Ctile; ct < 32; ++ct) {
        __syncthreads();  // prior reads of Kt/Vt/Pt complete
        stage64(base + (size_t)ct * 64 * 3072 + 1024 + a * 64, 3072, Kt, wave, lane);
        stage64(vt + (size_t)bh * 64 * 2048 + ct * 64, 2048, Vt, wave, lane);
        __syncthreads();

        bf16x8 a0 = *(const bf16x8*)&Kt[(wave * 16 + col) * 64 + quad * 8];
        bf16x8 a1 = *(const bf16x8*)&Kt[(wave * 16 + col) * 64 + 32 + quad * 8];

        float mr[4], rl[4];
#pragma unroll
        for (int r = 0; r < 4; ++r) {
            int c = ct * 64 + wave * 16 + quad * 4 + r;
            mr[r] = mstat[(size_t)bh * 2048 + c];
            rl[r] = 1.0f / lstat[(size_t)bh * 2048 + c];
        }
#pragma unroll
        for (int nt = 0; nt < 4; ++nt) {
            bf16x8 b0 = *(const bf16x8*)&Qt[(nt * 16 + col) * 64 + quad * 8];
            bf16x8 b1 = *(const bf16x8*)&Qt[(nt * 16 + col) * 64 + 32 + quad * 8];
            floatx4 acc = (floatx4){0.f, 0.f, 0.f, 0.f};
            acc = MFMA16(a0, b0, acc);
            acc = MFMA16(a1, b1, acc);
#pragma unroll
            for (int r = 0; r < 4; ++r) {
                float p;
                if (ct == Ctile && (nt * 16 + col) > (wave * 16 + quad * 4 + r))
                    p = 0.f;
                else
                    p = __expf(acc[r] * 0.125f - mr[r]) * rl[r];
                // transposed store: Pt[C_local][c_local]
                Pt[(nt * 16 + col) * 72 + wave * 16 + quad * 4 + r] = (bf16)p;
            }
        }
        __syncthreads();  // Pt visible to all waves

        bf16x8 v0 = *(const bf16x8*)&Vt[(wave * 16 + col) * 64 + quad * 8];
        bf16x8 v1 = *(const bf16x8*)&Vt[(wave * 16 + col) * 64 + 32 + quad * 8];
#pragma unroll
        for (int mi = 0; mi < 4; ++mi) {
            bf16x8 p0 = *(const bf16x8*)&Pt[(mi * 16 + col) * 72 + quad * 8];
            bf16x8 p1 = *(const bf16x8*)&Pt[(mi * 16 + col) * 72 + 32 + quad * 8];
            zacc[mi] = MFMA16(p0, v0, zacc[mi]);
            zacc[mi] = MFMA16(p1, v1, zacc[mi]);
        }
    }
#pragma unroll
    for (int mi = 0; mi < 4; ++mi)
#pragma unroll
        for (int r = 0; r < 4; ++r) {
            int Cg = Ctile * 64 + mi * 16 + quad * 4 + r;
            zb[(size_t)(b * 2048 + Cg) * 1024 + a * 64 + wave * 16 + col] =
                (bf16)zacc[mi][r];
        }
}

// ---------------------------------------------------------------------------
// Host launcher
// ---------------------------------------------------------------------------
extern "C" void kernel_launch(void* const* d_in, const int* in_sizes, int n_in,
                              void* d_out, int out_size, void* d_ws, size_t ws_size,
                              hipStream_t stream) {
    (void)in_sizes; (void)n_in; (void)out_size; (void)ws_size;
    const float* x    = (const float*)d_in[0];
    const float* WK   = (const float*)d_in[1];
    const float* WQ   = (const float*)d_in[2];
    const float* WV   = (const float*)d_in[3];
    const float* WO   = (const float*)d_in[4];
    const float* Win  = (const float*)d_in[5];
    const float* bin  = (const float*)d_in[6];
    const float* Wout = (const float*)d_in[7];
    const float* bout = (const float*)d_in[8];
    float* out = (float*)d_out;

    char* ws = (char*)d_ws;
    bf16*  xb   = (bf16*)(ws + 0);          //  8 MB  x (bf16)
    bf16*  wqkv = (bf16*)(ws + 8388608);    //  6 MB  [q;k;v] rows x 1024
    bf16*  wo   = (bf16*)(ws + 14680064);   //  2 MB
    bf16*  win  = (bf16*)(ws + 16777216);   //  8 MB
    bf16*  wout = (bf16*)(ws + 25165824);   //  8 MB
    bf16*  qkvb = (bf16*)(ws + 33554432);   // 24 MB  [4096 x 3072]
    bf16*  vtb  = (bf16*)(ws + 58720256);   //  8 MB  V^T [2048 x 2048]
    float* mst  = (float*)(ws + 67108864);  // 256 KB
    float* lst  = (float*)(ws + 67371008);  // 256 KB
    bf16*  zbuf = (bf16*)(ws + 67633152);   //  8 MB  z_flat [4096 x 1024]
    bf16*  xmid = (bf16*)(ws + 76021760);   //  8 MB  x + attn_out (bf16)
    bf16*  hbuf = (bf16*)(ws + 84410368);   // 32 MB  relu(h) [4096 x 4096]

    // bf16 conversions
    cvt_bf16<<<4096, 256, 0, stream>>>(x, xb, 4194304);
    cvt_bf16<<<1024, 256, 0, stream>>>(WQ, wqkv, 1048576);
    cvt_bf16<<<1024, 256, 0, stream>>>(WK, wqkv + 1048576, 1048576);
    cvt_bf16<<<1024, 256, 0, stream>>>(WV, wqkv + 2097152, 1048576);
    cvt_bf16<<<1024, 256, 0, stream>>>(WO, wo, 1048576);
    cvt_bf16<<<4096, 256, 0, stream>>>(Win, win, 4194304);
    cvt_bf16<<<4096, 256, 0, stream>>>(Wout, wout, 4194304);

    // QKV projection: [4096x1024] x [3072x1024]^T -> qkvb [4096x3072] bf16
    gemm128<0><<<dim3(24, 32), 256, 0, stream>>>(xb, 1024, wqkv, 1024, 1024,
                                                 nullptr, qkvb, 3072, nullptr, nullptr);
    // V transpose for pass-2 B-operand
    transpose_v<<<dim3(32, 32), 256, 0, stream>>>(qkvb, vtb);
    // attention
    attn_stats<<<dim3(32, 32), 256, 0, stream>>>(qkvb, mst, lst);
    attn_av<<<dim3(32, 32), 256, 0, stream>>>(qkvb, vtb, mst, lst, zbuf);
    // attn_out = z @ W_O^T + x  -> d_out (fp32) and xmid (bf16)
    gemm128<1><<<dim3(8, 32), 256, 0, stream>>>(zbuf, 1024, wo, 1024, 1024,
                                                out, xmid, 1024, nullptr, x);
    // h = relu(xmid @ W_in^T + b_in) -> hbuf bf16 [4096x4096]
    gemm128<2><<<dim3(32, 32), 256, 0, stream>>>(xmid, 1024, win, 1024, 1024,
                                                 nullptr, hbuf, 4096, bin, nullptr);
    // out += h @ W_out^T + b_out
    gemm128<3><<<dim3(8, 32), 256, 0, stream>>>(hbuf, 4096, wout, 4096, 4096,
                                                out, nullptr, 1024, bout, nullptr);
}

// Round 2
// 501.965 us; speedup vs baseline: 1.0486x; 1.0486x over previous
//
#include <hip/hip_runtime.h>
#include <hip/hip_bf16.h>
#include <cstdint>
#include <cstddef>

typedef __bf16 bf16;
typedef bf16 bf16x4 __attribute__((ext_vector_type(4)));
typedef bf16 bf16x8 __attribute__((ext_vector_type(8)));
typedef float floatx4 __attribute__((ext_vector_type(4)));

#define MFMA16(a, b, c) __builtin_amdgcn_mfma_f32_16x16x32_bf16((a), (b), (c), 0, 0, 0)

__device__ __forceinline__ void async16(const void* g, void* l) {
    __builtin_amdgcn_global_load_lds((const __attribute__((address_space(1))) void*)g,
                                     (__attribute__((address_space(3))) void*)l,
                                     16, 0, 0);
}

// stage a 64x64 bf16 tile (global row stride ldg elems) into LDS (row stride 64)
__device__ __forceinline__ void stage64(const bf16* g0, int ldg, bf16* lds, int wave, int lane) {
#pragma unroll
    for (int i = 0; i < 2; ++i) {
        int r0 = wave * 16 + i * 8;  // wave-uniform
        async16(g0 + (size_t)(r0 + (lane >> 3)) * ldg + (lane & 7) * 8,
                lds + r0 * 64);
    }
}

// ---------------------------------------------------------------------------
// One fused fp32->bf16 convert for x + all weights. 16384 blocks x 256 thr,
// 1024 elems per block.
// ---------------------------------------------------------------------------
__global__ __launch_bounds__(256) void cvt_all(const float* __restrict__ x,
                                               const float* __restrict__ WQ,
                                               const float* __restrict__ WK,
                                               const float* __restrict__ WV,
                                               const float* __restrict__ WO,
                                               const float* __restrict__ Win,
                                               const float* __restrict__ Wout,
                                               bf16* __restrict__ xb,
                                               bf16* __restrict__ wqkv,
                                               bf16* __restrict__ wo,
                                               bf16* __restrict__ win,
                                               bf16* __restrict__ wout) {
    int blk = blockIdx.x;
    const float* src;
    bf16* dst;
    int off;
    if (blk < 1024)      { src = WQ;   dst = wqkv;           off = blk; }
    else if (blk < 2048) { src = WK;   dst = wqkv + 1048576; off = blk - 1024; }
    else if (blk < 3072) { src = WV;   dst = wqkv + 2097152; off = blk - 2048; }
    else if (blk < 4096) { src = WO;   dst = wo;             off = blk - 3072; }
    else if (blk < 8192) { src = Win;  dst = win;            off = blk - 4096; }
    else if (blk < 12288){ src = Wout; dst = wout;           off = blk - 8192; }
    else                 { src = x;    dst = xb;             off = blk - 12288; }
    int i = off * 1024 + threadIdx.x * 4;
    float4 v = *(const float4*)(src + i);
    bf16x4 o = {(bf16)v.x, (bf16)v.y, (bf16)v.z, (bf16)v.w};
    *(bf16x4*)(dst + i) = o;
}

// ---------------------------------------------------------------------------
// bf16 GEMM, C[M,N] = A[M,K]*B[N,K]^T. 128xNT tile, BK=32, double-buffered
// LDS with single barrier per K-iter (prefetch overlaps MFMA phase).
// EPI 0: store bf16 to Cb
// EPI 1: v = acc + res; store fp32 Cf AND bf16 Cb
// EPI 2: v = relu(acc + bias[col]); store bf16 Cb
// EPI 3: v = acc + bias[col] + Cf; store fp32 Cf
// ---------------------------------------------------------------------------
template <int EPI, int NT>
__global__ __launch_bounds__(256) void gemm_dbuf(const bf16* __restrict__ A, int lda,
                                                 const bf16* __restrict__ B, int ldb, int K,
                                                 float* __restrict__ Cf, bf16* __restrict__ Cb,
                                                 int ldc, const float* __restrict__ bias,
                                                 const float* __restrict__ res) {
    constexpr int NACC = NT / 32;  // 4 (NT=128) or 2 (NT=64)
    __shared__ __align__(16) bf16 As[2][128 * 32];
    __shared__ __align__(16) bf16 Bs[2][NT * 32];
    const int tid = threadIdx.x, wave = tid >> 6, lane = tid & 63;
    const int m0 = blockIdx.y * 128, n0 = blockIdx.x * NT;
    const int wm = (wave >> 1) * 64, wn = (wave & 1) * (NT / 2);
    const int col = lane & 15, quad = lane >> 4;

    floatx4 acc[4][NACC];
#pragma unroll
    for (int mi = 0; mi < 4; ++mi)
#pragma unroll
        for (int ni = 0; ni < NACC; ++ni) acc[mi][ni] = (floatx4){0.f, 0.f, 0.f, 0.f};

    auto stage = [&](int buf, int k0) {
#pragma unroll
        for (int i = 0; i < 2; ++i) {
            int r0 = wave * 32 + i * 16;  // wave-uniform
            async16(A + (size_t)(m0 + r0 + (lane >> 2)) * lda + k0 + (lane & 3) * 8,
                    As[buf] + r0 * 32);
        }
        if constexpr (NT == 128) {
#pragma unroll
            for (int i = 0; i < 2; ++i) {
                int r0 = wave * 32 + i * 16;
                async16(B + (size_t)(n0 + r0 + (lane >> 2)) * ldb + k0 + (lane & 3) * 8,
                        Bs[buf] + r0 * 32);
            }
        } else {
            int r0 = wave * 16;
            async16(B + (size_t)(n0 + r0 + (lane >> 2)) * ldb + k0 + (lane & 3) * 8,
                    Bs[buf] + r0 * 32);
        }
    };

    stage(0, 0);
    const int nk = K / 32;
    for (int it = 0; it < nk; ++it) {
        __syncthreads();  // vmcnt(0) drain: cur buf arrived (had full MFMA phase);
                          // also: everyone's ds_reads of the other buf are done.
        if (it + 1 < nk) stage((it + 1) & 1, (it + 1) * 32);
        const int cur = it & 1;
        bf16x8 af[4], bfr[NACC];
#pragma unroll
        for (int mi = 0; mi < 4; ++mi)
            af[mi] = *(const bf16x8*)&As[cur][(wm + mi * 16 + col) * 32 + quad * 8];
#pragma unroll
        for (int ni = 0; ni < NACC; ++ni)
            bfr[ni] = *(const bf16x8*)&Bs[cur][(wn + ni * 16 + col) * 32 + quad * 8];
#pragma unroll
        for (int mi = 0; mi < 4; ++mi)
#pragma unroll
            for (int ni = 0; ni < NACC; ++ni)
                acc[mi][ni] = MFMA16(af[mi], bfr[ni], acc[mi][ni]);
    }

#pragma unroll
    for (int mi = 0; mi < 4; ++mi)
#pragma unroll
        for (int ni = 0; ni < NACC; ++ni)
#pragma unroll
            for (int r = 0; r < 4; ++r) {
                int row = m0 + wm + mi * 16 + quad * 4 + r;
                int cc = n0 + wn + ni * 16 + col;
                size_t idx = (size_t)row * ldc + cc;
                float v = acc[mi][ni][r];
                if constexpr (EPI == 0) {
                    Cb[idx] = (bf16)v;
                } else if constexpr (EPI == 1) {
                    v += res[idx];
                    Cf[idx] = v;
                    Cb[idx] = (bf16)v;
                } else if constexpr (EPI == 2) {
                    v += bias[cc];
                    v = fmaxf(v, 0.f);
                    Cb[idx] = (bf16)v;
                } else {
                    v += bias[cc] + Cf[idx];
                    Cf[idx] = v;
                }
            }
}

// ---------------------------------------------------------------------------
// Transpose V: qkv[b*2048+c][2048 + a*64 + h] -> vt[(bh*64+h)][c]
// ---------------------------------------------------------------------------
__global__ __launch_bounds__(256) void transpose_v(const bf16* __restrict__ qkv,
                                                   bf16* __restrict__ vt) {
    __shared__ bf16 t[64][65];
    const int bh = blockIdx.y, ct = blockIdx.x;
    const int b = bh >> 4, a = bh & 15;
    for (int idx = threadIdx.x; idx < 4096; idx += 256) {
        int c = idx >> 6, h = idx & 63;
        t[h][c] = qkv[(size_t)(b * 2048 + ct * 64 + c) * 3072 + 2048 + a * 64 + h];
    }
    __syncthreads();
    for (int idx = threadIdx.x; idx < 4096; idx += 256) {
        int h = idx >> 6, c = idx & 63;
        vt[(size_t)(bh * 64 + h) * 2048 + ct * 64 + c] = t[h][c];
    }
}

// ---------------------------------------------------------------------------
// Attention pass 1: per-row stats, softmax over C <= c of S[c][C]=(k_c.q_C)/8.
// Double-buffered Qt; zigzag ct map for triangular load balance.
// ---------------------------------------------------------------------------
__global__ __launch_bounds__(256) void attn_stats(const bf16* __restrict__ qkv,
                                                  float* __restrict__ mstat,
                                                  float* __restrict__ lstat) {
    __shared__ __align__(16) bf16 Kt[64 * 64];
    __shared__ __align__(16) bf16 Qt[2][64 * 64];
    const int xx = blockIdx.x;
    const int ct = (xx & 1) ? (31 - (xx >> 1)) : (xx >> 1);
    const int bh = blockIdx.y;
    const int b = bh >> 4, a = bh & 15;
    const int tid = threadIdx.x, wave = tid >> 6, lane = tid & 63;
    const int col = lane & 15, quad = lane >> 4;
    const bf16* base = qkv + (size_t)b * 2048 * 3072;

    stage64(base + (size_t)ct * 64 * 3072 + 1024 + a * 64, 3072, Kt, wave, lane);
    stage64(base + a * 64, 3072, Qt[0], wave, lane);  // Ct = 0

    float mrun[4], lrun[4];
#pragma unroll
    for (int r = 0; r < 4; ++r) { mrun[r] = -3e38f; lrun[r] = 0.f; }

    for (int Ct = 0; Ct <= ct; ++Ct) {
        __syncthreads();  // Qt[cur] (and Kt on first iter) arrived; prev reads done
        if (Ct < ct)
            stage64(base + (size_t)(Ct + 1) * 64 * 3072 + a * 64, 3072,
                    Qt[(Ct + 1) & 1], wave, lane);
        const bf16* q = Qt[Ct & 1];

        bf16x8 a0 = *(const bf16x8*)&Kt[(wave * 16 + col) * 64 + quad * 8];
        bf16x8 a1 = *(const bf16x8*)&Kt[(wave * 16 + col) * 64 + 32 + quad * 8];

        float s[4][4];
#pragma unroll
        for (int nt = 0; nt < 4; ++nt) {
            bf16x8 b0 = *(const bf16x8*)&q[(nt * 16 + col) * 64 + quad * 8];
            bf16x8 b1 = *(const bf16x8*)&q[(nt * 16 + col) * 64 + 32 + quad * 8];
            floatx4 sacc = (floatx4){0.f, 0.f, 0.f, 0.f};
            sacc = MFMA16(a0, b0, sacc);
            sacc = MFMA16(a1, b1, sacc);
#pragma unroll
            for (int r = 0; r < 4; ++r) {
                float v = sacc[r] * 0.125f;
                if (Ct == ct && (nt * 16 + col) > (wave * 16 + quad * 4 + r)) v = -3e38f;
                s[nt][r] = v;
            }
        }
#pragma unroll
        for (int r = 0; r < 4; ++r) {
            float tm = fmaxf(fmaxf(s[0][r], s[1][r]), fmaxf(s[2][r], s[3][r]));
            tm = fmaxf(tm, __shfl_xor(tm, 1));
            tm = fmaxf(tm, __shfl_xor(tm, 2));
            tm = fmaxf(tm, __shfl_xor(tm, 4));
            tm = fmaxf(tm, __shfl_xor(tm, 8));
            float nm = fmaxf(mrun[r], tm);
            float ts = __expf(s[0][r] - nm) + __expf(s[1][r] - nm) +
                       __expf(s[2][r] - nm) + __expf(s[3][r] - nm);
            ts += __shfl_xor(ts, 1);
            ts += __shfl_xor(ts, 2);
            ts += __shfl_xor(ts, 4);
            ts += __shfl_xor(ts, 8);
            lrun[r] = lrun[r] * __expf(mrun[r] - nm) + ts;
            mrun[r] = nm;
        }
    }
    if (col == 0) {
#pragma unroll
        for (int r = 0; r < 4; ++r) {
            int c = ct * 64 + wave * 16 + quad * 4 + r;
            mstat[(size_t)bh * 2048 + c] = mrun[r];
            lstat[(size_t)bh * 2048 + c] = lrun[r];
        }
    }
}

// ---------------------------------------------------------------------------
// Attention pass 2: z[C][h] = sum_{c>=C} P[c][C]*v[c][h]. Double-buffered
// Kt/Vt; zigzag Ctile map.
// ---------------------------------------------------------------------------
__global__ __launch_bounds__(256) void attn_av(const bf16* __restrict__ qkv,
                                               const bf16* __restrict__ vt,
                                               const float* __restrict__ mstat,
                                               const float* __restrict__ lstat,
                                               bf16* __restrict__ zb) {
    __shared__ __align__(16) bf16 Qt[64 * 64];
    __shared__ __align__(16) bf16 Kt[2][64 * 64];
    __shared__ __align__(16) bf16 Vt[2][64 * 64];
    __shared__ __align__(16) bf16 Pt[64 * 72];
    const int xx = blockIdx.x;
    const int Ctile = (xx & 1) ? (31 - (xx >> 1)) : (xx >> 1);
    const int bh = blockIdx.y;
    const int b = bh >> 4, a = bh & 15;
    const int tid = threadIdx.x, wave = tid >> 6, lane = tid & 63;
    const int col = lane & 15, quad = lane >> 4;
    const bf16* base = qkv + (size_t)b * 2048 * 3072;

    stage64(base + (size_t)Ctile * 64 * 3072 + a * 64, 3072, Qt, wave, lane);
    stage64(base + (size_t)Ctile * 64 * 3072 + 1024 + a * 64, 3072, Kt[0], wave, lane);
    stage64(vt + (size_t)bh * 64 * 2048 + Ctile * 64, 2048, Vt[0], wave, lane);

    floatx4 zacc[4];
#pragma unroll
    for (int mi = 0; mi < 4; ++mi) zacc[mi] = (floatx4){0.f, 0.f, 0.f, 0.f};

    for (int ct = Ctile; ct < 32; ++ct) {
        const int cur = (ct - Ctile) & 1;
        __syncthreads();  // cur K/V (+Qt first iter) arrived; Pt reads of prev iter done
        if (ct < 31) {
            stage64(base + (size_t)(ct + 1) * 64 * 3072 + 1024 + a * 64, 3072,
                    Kt[cur ^ 1], wave, lane);
            stage64(vt + (size_t)bh * 64 * 2048 + (ct + 1) * 64, 2048,
                    Vt[cur ^ 1], wave, lane);
        }

        bf16x8 a0 = *(const bf16x8*)&Kt[cur][(wave * 16 + col) * 64 + quad * 8];
        bf16x8 a1 = *(const bf16x8*)&Kt[cur][(wave * 16 + col) * 64 + 32 + quad * 8];

        float mr[4], rl[4];
#pragma unroll
        for (int r = 0; r < 4; ++r) {
            int c = ct * 64 + wave * 16 + quad * 4 + r;
            mr[r] = mstat[(size_t)bh * 2048 + c];
            rl[r] = 1.0f / lstat[(size_t)bh * 2048 + c];
        }
#pragma unroll
        for (int nt = 0; nt < 4; ++nt) {
            bf16x8 b0 = *(const bf16x8*)&Qt[(nt * 16 + col) * 64 + quad * 8];
            bf16x8 b1 = *(const bf16x8*)&Qt[(nt * 16 + col) * 64 + 32 + quad * 8];
            floatx4 sacc = (floatx4){0.f, 0.f, 0.f, 0.f};
            sacc = MFMA16(a0, b0, sacc);
            sacc = MFMA16(a1, b1, sacc);
#pragma unroll
            for (int r = 0; r < 4; ++r) {
                float p;
                if (ct == Ctile && (nt * 16 + col) > (wave * 16 + quad * 4 + r))
                    p = 0.f;
                else
                    p = __expf(sacc[r] * 0.125f - mr[r]) * rl[r];
                Pt[(nt * 16 + col) * 72 + wave * 16 + quad * 4 + r] = (bf16)p;
            }
        }
        __syncthreads();  // Pt visible (also drains prefetch early; window = S+exp phase)

        bf16x8 v0 = *(const bf16x8*)&Vt[cur][(wave * 16 + col) * 64 + quad * 8];
        bf16x8 v1 = *(const bf16x8*)&Vt[cur][(wave * 16 + col) * 64 + 32 + quad * 8];
#pragma unroll
        for (int mi = 0; mi < 4; ++mi) {
            bf16x8 p0 = *(const bf16x8*)&Pt[(mi * 16 + col) * 72 + quad * 8];
            bf16x8 p1 = *(const bf16x8*)&Pt[(mi * 16 + col) * 72 + 32 + quad * 8];
            zacc[mi] = MFMA16(p0, v0, zacc[mi]);
            zacc[mi] = MFMA16(p1, v1, zacc[mi]);
        }
    }
#pragma unroll
    for (int mi = 0; mi < 4; ++mi)
#pragma unroll
        for (int r = 0; r < 4; ++r) {
            int Cg = Ctile * 64 + mi * 16 + quad * 4 + r;
            zb[(size_t)(b * 2048 + Cg) * 1024 + a * 64 + wave * 16 + col] =
                (bf16)zacc[mi][r];
        }
}

// ---------------------------------------------------------------------------
// Host launcher
// ---------------------------------------------------------------------------
extern "C" void kernel_launch(void* const* d_in, const int* in_sizes, int n_in,
                              void* d_out, int out_size, void* d_ws, size_t ws_size,
                              hipStream_t stream) {
    (void)in_sizes; (void)n_in; (void)out_size; (void)ws_size;
    const float* x    = (const float*)d_in[0];
    const float* WK   = (const float*)d_in[1];
    const float* WQ   = (const float*)d_in[2];
    const float* WV   = (const float*)d_in[3];
    const float* WO   = (const float*)d_in[4];
    const float* Win  = (const float*)d_in[5];
    const float* bin  = (const float*)d_in[6];
    const float* Wout = (const float*)d_in[7];
    const float* bout = (const float*)d_in[8];
    float* out = (float*)d_out;

    char* ws = (char*)d_ws;
    bf16*  xb   = (bf16*)(ws + 0);          //  8 MB
    bf16*  wqkv = (bf16*)(ws + 8388608);    //  6 MB
    bf16*  wo   = (bf16*)(ws + 14680064);   //  2 MB
    bf16*  win  = (bf16*)(ws + 16777216);   //  8 MB
    bf16*  wout = (bf16*)(ws + 25165824);   //  8 MB
    bf16*  qkvb = (bf16*)(ws + 33554432);   // 24 MB
    bf16*  vtb  = (bf16*)(ws + 58720256);   //  8 MB
    float* mst  = (float*)(ws + 67108864);  // 256 KB
    float* lst  = (float*)(ws + 67371008);  // 256 KB
    bf16*  zbuf = (bf16*)(ws + 67633152);   //  8 MB
    bf16*  xmid = (bf16*)(ws + 76021760);   //  8 MB
    bf16*  hbuf = (bf16*)(ws + 84410368);   // 32 MB

    cvt_all<<<16384, 256, 0, stream>>>(x, WQ, WK, WV, WO, Win, Wout,
                                       xb, wqkv, wo, win, wout);

    // QKV projection: [4096x1024] x [3072x1024]^T -> qkvb
    gemm_dbuf<0, 128><<<dim3(24, 32), 256, 0, stream>>>(xb, 1024, wqkv, 1024, 1024,
                                                        nullptr, qkvb, 3072, nullptr, nullptr);
    transpose_v<<<dim3(32, 32), 256, 0, stream>>>(qkvb, vtb);
    attn_stats<<<dim3(32, 32), 256, 0, stream>>>(qkvb, mst, lst);
    attn_av<<<dim3(32, 32), 256, 0, stream>>>(qkvb, vtb, mst, lst, zbuf);
    // attn_out = z @ W_O^T + x
    gemm_dbuf<1, 64><<<dim3(16, 32), 256, 0, stream>>>(zbuf, 1024, wo, 1024, 1024,
                                                       out, xmid, 1024, nullptr, x);
    // h = relu(xmid @ W_in^T + b_in)
    gemm_dbuf<2, 128><<<dim3(32, 32), 256, 0, stream>>>(xmid, 1024, win, 1024, 1024,
                                                        nullptr, hbuf, 4096, bin, nullptr);
    // out += h @ W_out^T + b_out
    gemm_dbuf<3, 64><<<dim3(16, 32), 256, 0, stream>>>(hbuf, 4096, wout, 4096, 4096,
                                                       out, nullptr, 1024, bout, nullptr);
}

// Round 3
// 419.078 us; speedup vs baseline: 1.2560x; 1.1978x over previous
//
#include <hip/hip_runtime.h>
#include <hip/hip_bf16.h>
#include <cstdint>
#include <cstddef>

typedef __bf16 bf16;
typedef bf16 bf16x4 __attribute__((ext_vector_type(4)));
typedef bf16 bf16x8 __attribute__((ext_vector_type(8)));
typedef float floatx4 __attribute__((ext_vector_type(4)));

#define MFMA16(a, b, c) __builtin_amdgcn_mfma_f32_16x16x32_bf16((a), (b), (c), 0, 0, 0)

// log2(e)/8: S is the RAW k.q dot; softmax uses exp(S/8) = exp2(S*K2)
#define K2 0.18033688011112042f

__device__ __forceinline__ void async16(const void* g, void* l) {
    __builtin_amdgcn_global_load_lds((const __attribute__((address_space(1))) void*)g,
                                     (__attribute__((address_space(3))) void*)l,
                                     16, 0, 0);
}

__device__ __forceinline__ void stage64(const bf16* g0, int ldg, bf16* lds, int wave, int lane) {
#pragma unroll
    for (int i = 0; i < 2; ++i) {
        int r0 = wave * 16 + i * 8;  // wave-uniform
        async16(g0 + (size_t)(r0 + (lane >> 3)) * ldg + (lane & 7) * 8,
                lds + r0 * 64);
    }
}

// raw barriers: avoid __syncthreads' full vmcnt(0)+lgkmcnt(0) drain
#define BAR_VM()                                              \
    do {                                                      \
        asm volatile("s_waitcnt vmcnt(0)" ::: "memory");      \
        __builtin_amdgcn_s_barrier();                         \
    } while (0)
#define BAR_LGKM()                                            \
    do {                                                      \
        asm volatile("s_waitcnt lgkmcnt(0)" ::: "memory");    \
        __builtin_amdgcn_s_barrier();                         \
    } while (0)

// ---------------------------------------------------------------------------
// Fused fp32->bf16 convert
// ---------------------------------------------------------------------------
__global__ __launch_bounds__(256) void cvt_all(const float* __restrict__ x,
                                               const float* __restrict__ WQ,
                                               const float* __restrict__ WK,
                                               const float* __restrict__ WV,
                                               const float* __restrict__ WO,
                                               const float* __restrict__ Win,
                                               const float* __restrict__ Wout,
                                               bf16* __restrict__ xb,
                                               bf16* __restrict__ wqkv,
                                               bf16* __restrict__ wo,
                                               bf16* __restrict__ win,
                                               bf16* __restrict__ wout) {
    int blk = blockIdx.x;
    const float* src;
    bf16* dst;
    int off;
    if (blk < 1024)      { src = WQ;   dst = wqkv;           off = blk; }
    else if (blk < 2048) { src = WK;   dst = wqkv + 1048576; off = blk - 1024; }
    else if (blk < 3072) { src = WV;   dst = wqkv + 2097152; off = blk - 2048; }
    else if (blk < 4096) { src = WO;   dst = wo;             off = blk - 3072; }
    else if (blk < 8192) { src = Win;  dst = win;            off = blk - 4096; }
    else if (blk < 12288){ src = Wout; dst = wout;           off = blk - 8192; }
    else                 { src = x;    dst = xb;             off = blk - 12288; }
    int i = off * 1024 + threadIdx.x * 4;
    float4 v = *(const float4*)(src + i);
    bf16x4 o = {(bf16)v.x, (bf16)v.y, (bf16)v.z, (bf16)v.w};
    *(bf16x4*)(dst + i) = o;
}

// ---------------------------------------------------------------------------
// bf16 GEMM, C[M,N] = A[M,K]*B[N,K]^T. 128xNT tile, BK=32, dbuf LDS.
// ---------------------------------------------------------------------------
template <int EPI, int NT>
__global__ __launch_bounds__(256) void gemm_dbuf(const bf16* __restrict__ A, int lda,
                                                 const bf16* __restrict__ B, int ldb, int K,
                                                 float* __restrict__ Cf, bf16* __restrict__ Cb,
                                                 int ldc, const float* __restrict__ bias,
                                                 const float* __restrict__ res) {
    constexpr int NACC = NT / 32;
    __shared__ __align__(16) bf16 As[2][128 * 32];
    __shared__ __align__(16) bf16 Bs[2][NT * 32];
    const int tid = threadIdx.x, wave = tid >> 6, lane = tid & 63;
    const int m0 = blockIdx.y * 128, n0 = blockIdx.x * NT;
    const int wm = (wave >> 1) * 64, wn = (wave & 1) * (NT / 2);
    const int col = lane & 15, quad = lane >> 4;

    floatx4 acc[4][NACC];
#pragma unroll
    for (int mi = 0; mi < 4; ++mi)
#pragma unroll
        for (int ni = 0; ni < NACC; ++ni) acc[mi][ni] = (floatx4){0.f, 0.f, 0.f, 0.f};

    auto stage = [&](int buf, int k0) {
#pragma unroll
        for (int i = 0; i < 2; ++i) {
            int r0 = wave * 32 + i * 16;
            async16(A + (size_t)(m0 + r0 + (lane >> 2)) * lda + k0 + (lane & 3) * 8,
                    As[buf] + r0 * 32);
        }
        if constexpr (NT == 128) {
#pragma unroll
            for (int i = 0; i < 2; ++i) {
                int r0 = wave * 32 + i * 16;
                async16(B + (size_t)(n0 + r0 + (lane >> 2)) * ldb + k0 + (lane & 3) * 8,
                        Bs[buf] + r0 * 32);
            }
        } else {
            int r0 = wave * 16;
            async16(B + (size_t)(n0 + r0 + (lane >> 2)) * ldb + k0 + (lane & 3) * 8,
                    Bs[buf] + r0 * 32);
        }
    };

    stage(0, 0);
    const int nk = K / 32;
    for (int it = 0; it < nk; ++it) {
        __syncthreads();
        if (it + 1 < nk) stage((it + 1) & 1, (it + 1) * 32);
        const int cur = it & 1;
        bf16x8 af[4], bfr[NACC];
#pragma unroll
        for (int mi = 0; mi < 4; ++mi)
            af[mi] = *(const bf16x8*)&As[cur][(wm + mi * 16 + col) * 32 + quad * 8];
#pragma unroll
        for (int ni = 0; ni < NACC; ++ni)
            bfr[ni] = *(const bf16x8*)&Bs[cur][(wn + ni * 16 + col) * 32 + quad * 8];
#pragma unroll
        for (int mi = 0; mi < 4; ++mi)
#pragma unroll
            for (int ni = 0; ni < NACC; ++ni)
                acc[mi][ni] = MFMA16(af[mi], bfr[ni], acc[mi][ni]);
    }

#pragma unroll
    for (int mi = 0; mi < 4; ++mi)
#pragma unroll
        for (int ni = 0; ni < NACC; ++ni)
#pragma unroll
            for (int r = 0; r < 4; ++r) {
                int row = m0 + wm + mi * 16 + quad * 4 + r;
                int cc = n0 + wn + ni * 16 + col;
                size_t idx = (size_t)row * ldc + cc;
                float v = acc[mi][ni][r];
                if constexpr (EPI == 0) {
                    Cb[idx] = (bf16)v;
                } else if constexpr (EPI == 1) {
                    v += res[idx];
                    Cf[idx] = v;
                    Cb[idx] = (bf16)v;
                } else if constexpr (EPI == 2) {
                    v += bias[cc];
                    v = fmaxf(v, 0.f);
                    Cb[idx] = (bf16)v;
                } else {
                    v += bias[cc] + Cf[idx];
                    Cf[idx] = v;
                }
            }
}

// ---------------------------------------------------------------------------
// Transpose V
// ---------------------------------------------------------------------------
__global__ __launch_bounds__(256) void transpose_v(const bf16* __restrict__ qkv,
                                                   bf16* __restrict__ vt) {
    __shared__ bf16 t[64][65];
    const int bh = blockIdx.y, ct = blockIdx.x;
    const int b = bh >> 4, a = bh & 15;
    for (int idx = threadIdx.x; idx < 4096; idx += 256) {
        int c = idx >> 6, h = idx & 63;
        t[h][c] = qkv[(size_t)(b * 2048 + ct * 64 + c) * 3072 + 2048 + a * 64 + h];
    }
    __syncthreads();
    for (int idx = threadIdx.x; idx < 4096; idx += 256) {
        int h = idx >> 6, c = idx & 63;
        vt[(size_t)(bh * 64 + h) * 2048 + ct * 64 + c] = t[h][c];
    }
}

// ---------------------------------------------------------------------------
// Attention pass 1: l_c = sum_{C<=c} exp(S[c][C]/8), no max (scores are
// O(10), f32-safe). Stores mp2[c] = log2(l_c); pass 2 computes
// P = exp2(S*K2 - mp2). Per-lane accumulation, single butterfly at end.
// ---------------------------------------------------------------------------
__global__ __launch_bounds__(256) void attn_stats(const bf16* __restrict__ qkv,
                                                  float* __restrict__ mp2) {
    __shared__ __align__(16) bf16 Kt[64 * 64];
    __shared__ __align__(16) bf16 Qt[2][64 * 64];
    const int xx = blockIdx.x;
    const int ct = (xx & 1) ? (31 - (xx >> 1)) : (xx >> 1);
    const int bh = blockIdx.y;
    const int b = bh >> 4, a = bh & 15;
    const int tid = threadIdx.x, wave = tid >> 6, lane = tid & 63;
    const int col = lane & 15, quad = lane >> 4;
    const bf16* base = qkv + (size_t)b * 2048 * 3072;

    stage64(base + (size_t)ct * 64 * 3072 + 1024 + a * 64, 3072, Kt, wave, lane);
    stage64(base + a * 64, 3072, Qt[0], wave, lane);

    float lrun[4] = {0.f, 0.f, 0.f, 0.f};
    bf16x8 a0, a1;

    for (int Ct = 0; Ct <= ct; ++Ct) {
        __syncthreads();  // Qt[cur] (and Kt first iter) arrived; prev-buf reads done
        if (Ct < ct)
            stage64(base + (size_t)(Ct + 1) * 64 * 3072 + a * 64, 3072,
                    Qt[(Ct + 1) & 1], wave, lane);
        if (Ct == 0) {
            a0 = *(const bf16x8*)&Kt[(wave * 16 + col) * 64 + quad * 8];
            a1 = *(const bf16x8*)&Kt[(wave * 16 + col) * 64 + 32 + quad * 8];
        }
        const bf16* q = Qt[Ct & 1];
#pragma unroll
        for (int nt = 0; nt < 4; ++nt) {
            bf16x8 b0 = *(const bf16x8*)&q[(nt * 16 + col) * 64 + quad * 8];
            bf16x8 b1 = *(const bf16x8*)&q[(nt * 16 + col) * 64 + 32 + quad * 8];
            floatx4 sacc = (floatx4){0.f, 0.f, 0.f, 0.f};
            sacc = MFMA16(a0, b0, sacc);
            sacc = MFMA16(a1, b1, sacc);
#pragma unroll
            for (int r = 0; r < 4; ++r) {
                float e = __builtin_amdgcn_exp2f(sacc[r] * K2);
                if (Ct == ct && (nt * 16 + col) > (wave * 16 + quad * 4 + r)) e = 0.f;
                lrun[r] += e;
            }
        }
    }
#pragma unroll
    for (int r = 0; r < 4; ++r) {
        float t = lrun[r];
        t += __shfl_xor(t, 1);
        t += __shfl_xor(t, 2);
        t += __shfl_xor(t, 4);
        t += __shfl_xor(t, 8);
        lrun[r] = t;
    }
    if (col == 0) {
#pragma unroll
        for (int r = 0; r < 4; ++r) {
            int c = ct * 64 + wave * 16 + quad * 4 + r;
            mp2[(size_t)bh * 2048 + c] = __builtin_amdgcn_logf(lrun[r]);
        }
    }
}

// ---------------------------------------------------------------------------
// Attention pass 2: z[C][h] = sum_{c>=C} P[c][C]*v[c][h],
// P = exp2(S*K2 - mp2[c]). Q frags hoisted; stats software-pipelined;
// raw barriers keep K/V DMA prefetch in flight across the Pt barrier.
// ---------------------------------------------------------------------------
__global__ __launch_bounds__(256) void attn_av(const bf16* __restrict__ qkv,
                                               const bf16* __restrict__ vt,
                                               const float* __restrict__ mp2,
                                               bf16* __restrict__ zb) {
    __shared__ __align__(16) bf16 Qt[64 * 64];
    __shared__ __align__(16) bf16 Kt[2][64 * 64];
    __shared__ __align__(16) bf16 Vt[2][64 * 64];
    __shared__ __align__(16) bf16 Pt[64 * 72];
    const int xx = blockIdx.x;
    const int Ctile = (xx & 1) ? (31 - (xx >> 1)) : (xx >> 1);
    const int bh = blockIdx.y;
    const int b = bh >> 4, a = bh & 15;
    const int tid = threadIdx.x, wave = tid >> 6, lane = tid & 63;
    const int col = lane & 15, quad = lane >> 4;
    const bf16* base = qkv + (size_t)b * 2048 * 3072;
    const float* mpb = mp2 + (size_t)bh * 2048;

    stage64(base + (size_t)Ctile * 64 * 3072 + a * 64, 3072, Qt, wave, lane);
    stage64(base + (size_t)Ctile * 64 * 3072 + 1024 + a * 64, 3072, Kt[0], wave, lane);
    stage64(vt + (size_t)bh * 64 * 2048 + Ctile * 64, 2048, Vt[0], wave, lane);

    float4 mp_cur = *(const float4*)&mpb[Ctile * 64 + wave * 16 + quad * 4];

    floatx4 zacc[4];
#pragma unroll
    for (int mi = 0; mi < 4; ++mi) zacc[mi] = (floatx4){0.f, 0.f, 0.f, 0.f};
    bf16x8 qf0[4], qf1[4];

    for (int ct = Ctile; ct < 32; ++ct) {
        const int cur = (ct - Ctile) & 1;
        BAR_VM();  // this iter's K/V (+Qt first iter) arrived; Pt reads of prev iter done
        if (ct + 1 < 32) {  // full-iteration prefetch window (no drain at mid barrier)
            stage64(base + (size_t)(ct + 1) * 64 * 3072 + 1024 + a * 64, 3072,
                    Kt[cur ^ 1], wave, lane);
            stage64(vt + (size_t)bh * 64 * 2048 + (ct + 1) * 64, 2048,
                    Vt[cur ^ 1], wave, lane);
        }
        if (ct == Ctile) {
#pragma unroll
            for (int nt = 0; nt < 4; ++nt) {
                qf0[nt] = *(const bf16x8*)&Qt[(nt * 16 + col) * 64 + quad * 8];
                qf1[nt] = *(const bf16x8*)&Qt[(nt * 16 + col) * 64 + 32 + quad * 8];
            }
        }
        bf16x8 a0 = *(const bf16x8*)&Kt[cur][(wave * 16 + col) * 64 + quad * 8];
        bf16x8 a1 = *(const bf16x8*)&Kt[cur][(wave * 16 + col) * 64 + 32 + quad * 8];

        const float mpl[4] = {mp_cur.x, mp_cur.y, mp_cur.z, mp_cur.w};
#pragma unroll
        for (int nt = 0; nt < 4; ++nt) {
            floatx4 sacc = (floatx4){0.f, 0.f, 0.f, 0.f};
            sacc = MFMA16(a0, qf0[nt], sacc);
            sacc = MFMA16(a1, qf1[nt], sacc);
            bf16x4 pv;
#pragma unroll
            for (int r = 0; r < 4; ++r) {
                float p;
                if (ct == Ctile && (nt * 16 + col) > (wave * 16 + quad * 4 + r))
                    p = 0.f;
                else
                    p = __builtin_amdgcn_exp2f(sacc[r] * K2 - mpl[r]);
                pv[r] = (bf16)p;
            }
            *(bf16x4*)&Pt[(nt * 16 + col) * 72 + wave * 16 + quad * 4] = pv;
        }
        BAR_LGKM();  // Pt visible; K/V DMA for ct+1 still in flight

        float4 mp_nxt = mp_cur;
        if (ct + 1 < 32)
            mp_nxt = *(const float4*)&mpb[(ct + 1) * 64 + wave * 16 + quad * 4];

        bf16x8 v0 = *(const bf16x8*)&Vt[cur][(wave * 16 + col) * 64 + quad * 8];
        bf16x8 v1 = *(const bf16x8*)&Vt[cur][(wave * 16 + col) * 64 + 32 + quad * 8];
#pragma unroll
        for (int mi = 0; mi < 4; ++mi) {
            bf16x8 p0 = *(const bf16x8*)&Pt[(mi * 16 + col) * 72 + quad * 8];
            bf16x8 p1 = *(const bf16x8*)&Pt[(mi * 16 + col) * 72 + 32 + quad * 8];
            zacc[mi] = MFMA16(p0, v0, zacc[mi]);
            zacc[mi] = MFMA16(p1, v1, zacc[mi]);
        }
        mp_cur = mp_nxt;
    }
#pragma unroll
    for (int mi = 0; mi < 4; ++mi)
#pragma unroll
        for (int r = 0; r < 4; ++r) {
            int Cg = Ctile * 64 + mi * 16 + quad * 4 + r;
            zb[(size_t)(b * 2048 + Cg) * 1024 + a * 64 + wave * 16 + col] =
                (bf16)zacc[mi][r];
        }
}

// ---------------------------------------------------------------------------
// Host launcher
// ---------------------------------------------------------------------------
extern "C" void kernel_launch(void* const* d_in, const int* in_sizes, int n_in,
                              void* d_out, int out_size, void* d_ws, size_t ws_size,
                              hipStream_t stream) {
    (void)in_sizes; (void)n_in; (void)out_size; (void)ws_size;
    const float* x    = (const float*)d_in[0];
    const float* WK   = (const float*)d_in[1];
    const float* WQ   = (const float*)d_in[2];
    const float* WV   = (const float*)d_in[3];
    const float* WO   = (const float*)d_in[4];
    const float* Win  = (const float*)d_in[5];
    const float* bin  = (const float*)d_in[6];
    const float* Wout = (const float*)d_in[7];
    const float* bout = (const float*)d_in[8];
    float* out = (float*)d_out;

    char* ws = (char*)d_ws;
    bf16*  xb   = (bf16*)(ws + 0);          //  8 MB
    bf16*  wqkv = (bf16*)(ws + 8388608);    //  6 MB
    bf16*  wo   = (bf16*)(ws + 14680064);   //  2 MB
    bf16*  win  = (bf16*)(ws + 16777216);   //  8 MB
    bf16*  wout = (bf16*)(ws + 25165824);   //  8 MB
    bf16*  qkvb = (bf16*)(ws + 33554432);   // 24 MB
    bf16*  vtb  = (bf16*)(ws + 58720256);   //  8 MB
    float* mst  = (float*)(ws + 67108864);  // 256 KB (mp2)
    bf16*  zbuf = (bf16*)(ws + 67633152);   //  8 MB
    bf16*  xmid = (bf16*)(ws + 76021760);   //  8 MB
    bf16*  hbuf = (bf16*)(ws + 84410368);   // 32 MB

    cvt_all<<<16384, 256, 0, stream>>>(x, WQ, WK, WV, WO, Win, Wout,
                                       xb, wqkv, wo, win, wout);

    gemm_dbuf<0, 128><<<dim3(24, 32), 256, 0, stream>>>(xb, 1024, wqkv, 1024, 1024,
                                                        nullptr, qkvb, 3072, nullptr, nullptr);
    transpose_v<<<dim3(32, 32), 256, 0, stream>>>(qkvb, vtb);
    attn_stats<<<dim3(32, 32), 256, 0, stream>>>(qkvb, mst);
    attn_av<<<dim3(32, 32), 256, 0, stream>>>(qkvb, vtb, mst, zbuf);
    gemm_dbuf<1, 64><<<dim3(16, 32), 256, 0, stream>>>(zbuf, 1024, wo, 1024, 1024,
                                                       out, xmid, 1024, nullptr, x);
    gemm_dbuf<2, 128><<<dim3(32, 32), 256, 0, stream>>>(xmid, 1024, win, 1024, 1024,
                                                        nullptr, hbuf, 4096, bin, nullptr);
    gemm_dbuf<3, 64><<<dim3(16, 32), 256, 0, stream>>>(hbuf, 4096, wout, 4096, 4096,
                                                       out, nullptr, 1024, bout, nullptr);
}

// Round 5
// 410.444 us; speedup vs baseline: 1.2824x; 1.0210x over previous
//
#include <hip/hip_runtime.h>
#include <hip/hip_bf16.h>
#include <cstdint>
#include <cstddef>

typedef __bf16 bf16;
typedef bf16 bf16x4 __attribute__((ext_vector_type(4)));
typedef bf16 bf16x8 __attribute__((ext_vector_type(8)));
typedef float floatx4 __attribute__((ext_vector_type(4)));

#define MFMA16(a, b, c) __builtin_amdgcn_mfma_f32_16x16x32_bf16((a), (b), (c), 0, 0, 0)

// log2(e)/8: S is the RAW k.q dot; softmax uses exp(S/8) = exp2(S*K2)
#define K2 0.18033688011112042f

__device__ __forceinline__ void async16(const void* g, void* l) {
    __builtin_amdgcn_global_load_lds((const __attribute__((address_space(1))) void*)g,
                                     (__attribute__((address_space(3))) void*)l,
                                     16, 0, 0);
}

// --- swizzled 64x64 bf16 tile stage (rows of 64 elems = 8 chunks of 16B).
// chunk' = chunk ^ (row&7) applied on the GLOBAL source address; LDS dest
// stays contiguous (DMA requirement). Reads use rd64().
__device__ __forceinline__ void stage64s(const bf16* g0, int ldg, bf16* lds, int wave, int lane) {
#pragma unroll
    for (int i = 0; i < 2; ++i) {
        int r0 = wave * 16 + i * 8;  // wave-uniform, multiple of 8
        async16(g0 + (size_t)(r0 + (lane >> 3)) * ldg + ((lane & 7) ^ (lane >> 3)) * 8,
                lds + r0 * 64);
    }
}
__device__ __forceinline__ bf16x8 rd64(const bf16* t, int row, int chunk) {
    return *(const bf16x8*)&t[row * 64 + ((chunk ^ (row & 7)) * 8)];
}
// --- 32-elem rows (GEMM BK=32): 4 chunks, 2-bit XOR
__device__ __forceinline__ bf16x8 rd32(const bf16* t, int row, int quad) {
    return *(const bf16x8*)&t[row * 32 + ((quad ^ (row & 3)) * 8)];
}

// ---------------------------------------------------------------------------
// Fused fp32->bf16 convert
// ---------------------------------------------------------------------------
__global__ __launch_bounds__(256) void cvt_all(const float* __restrict__ x,
                                               const float* __restrict__ WQ,
                                               const float* __restrict__ WK,
                                               const float* __restrict__ WV,
                                               const float* __restrict__ WO,
                                               const float* __restrict__ Win,
                                               const float* __restrict__ Wout,
                                               bf16* __restrict__ xb,
                                               bf16* __restrict__ wqkv,
                                               bf16* __restrict__ wo,
                                               bf16* __restrict__ win,
                                               bf16* __restrict__ wout) {
    int blk = blockIdx.x;
    const float* src;
    bf16* dst;
    int off;
    if (blk < 1024)      { src = WQ;   dst = wqkv;           off = blk; }
    else if (blk < 2048) { src = WK;   dst = wqkv + 1048576; off = blk - 1024; }
    else if (blk < 3072) { src = WV;   dst = wqkv + 2097152; off = blk - 2048; }
    else if (blk < 4096) { src = WO;   dst = wo;             off = blk - 3072; }
    else if (blk < 8192) { src = Win;  dst = win;            off = blk - 4096; }
    else if (blk < 12288){ src = Wout; dst = wout;           off = blk - 8192; }
    else                 { src = x;    dst = xb;             off = blk - 12288; }
    int i = off * 1024 + threadIdx.x * 4;
    float4 v = *(const float4*)(src + i);
    bf16x4 o = {(bf16)v.x, (bf16)v.y, (bf16)v.z, (bf16)v.w};
    *(bf16x4*)(dst + i) = o;
}

// ---------------------------------------------------------------------------
// bf16 GEMM, C[M,N] = A[M,K]*B[N,K]^T. 128xNT tile, BK=32.
// 3-stage LDS pipeline, raw barriers, fine-grained vmcnt (prefetch depth 2).
// ---------------------------------------------------------------------------
template <int EPI, int NT>
__global__ __launch_bounds__(256) void gemm_pipe(const bf16* __restrict__ A, int lda,
                                                 const bf16* __restrict__ B, int ldb, int K,
                                                 float* __restrict__ Cf, bf16* __restrict__ Cb,
                                                 int ldc, const float* __restrict__ bias,
                                                 const float* __restrict__ res) {
    constexpr int NACC = NT / 32;
    __shared__ __align__(16) bf16 As[3][128 * 32];
    __shared__ __align__(16) bf16 Bs[3][NT * 32];
    const int tid = threadIdx.x, wave = tid >> 6, lane = tid & 63;
    const int m0 = blockIdx.y * 128, n0 = blockIdx.x * NT;
    const int wm = (wave >> 1) * 64, wn = (wave & 1) * (NT / 2);
    const int col = lane & 15, quad = lane >> 4;
    const int cs8 = ((lane & 3) ^ ((lane >> 2) & 3)) * 8;  // 2-bit chunk swizzle

    floatx4 acc[4][NACC];
#pragma unroll
    for (int mi = 0; mi < 4; ++mi)
#pragma unroll
        for (int ni = 0; ni < NACC; ++ni) acc[mi][ni] = (floatx4){0.f, 0.f, 0.f, 0.f};

    auto stage = [&](int buf, int k0) {
#pragma unroll
        for (int i = 0; i < 2; ++i) {
            int r0 = wave * 32 + i * 16;  // multiple of 16 -> row&3 = (lane>>2)&3
            async16(A + (size_t)(m0 + r0 + (lane >> 2)) * lda + k0 + cs8,
                    As[buf] + r0 * 32);
        }
        if constexpr (NT == 128) {
#pragma unroll
            for (int i = 0; i < 2; ++i) {
                int r0 = wave * 32 + i * 16;
                async16(B + (size_t)(n0 + r0 + (lane >> 2)) * ldb + k0 + cs8,
                        Bs[buf] + r0 * 32);
            }
        } else {
            int r0 = wave * 16;
            async16(B + (size_t)(n0 + r0 + (lane >> 2)) * ldb + k0 + cs8,
                    Bs[buf] + r0 * 32);
        }
    };

    const int nk = K / 32;
    stage(0, 0);
    stage(1, 32);
    for (int it = 0; it < nk; ++it) {
        // wait for stage(it) only; stage(it+1) (newest loads) stays in flight
        if (it + 1 < nk) {
            if constexpr (NT == 128) asm volatile("s_waitcnt vmcnt(4)" ::: "memory");
            else                     asm volatile("s_waitcnt vmcnt(3)" ::: "memory");
        } else {
            asm volatile("s_waitcnt vmcnt(0)" ::: "memory");
        }
        __builtin_amdgcn_s_barrier();
        if (it + 2 < nk) stage((it + 2) % 3, (it + 2) * 32);

        const bf16* as = As[it % 3];
        const bf16* bs = Bs[it % 3];
        bf16x8 af[4], bfr[NACC];
#pragma unroll
        for (int mi = 0; mi < 4; ++mi) af[mi] = rd32(as, wm + mi * 16 + col, quad);
#pragma unroll
        for (int ni = 0; ni < NACC; ++ni) bfr[ni] = rd32(bs, wn + ni * 16 + col, quad);
#pragma unroll
        for (int mi = 0; mi < 4; ++mi)
#pragma unroll
            for (int ni = 0; ni < NACC; ++ni)
                acc[mi][ni] = MFMA16(af[mi], bfr[ni], acc[mi][ni]);
    }

#pragma unroll
    for (int mi = 0; mi < 4; ++mi)
#pragma unroll
        for (int ni = 0; ni < NACC; ++ni)
#pragma unroll
            for (int r = 0; r < 4; ++r) {
                int row = m0 + wm + mi * 16 + quad * 4 + r;
                int cc = n0 + wn + ni * 16 + col;
                size_t idx = (size_t)row * ldc + cc;
                float v = acc[mi][ni][r];
                if constexpr (EPI == 0) {
                    Cb[idx] = (bf16)v;
                } else if constexpr (EPI == 1) {
                    v += res[idx];
                    Cf[idx] = v;
                    Cb[idx] = (bf16)v;
                } else if constexpr (EPI == 2) {
                    v += bias[cc];
                    v = fmaxf(v, 0.f);
                    Cb[idx] = (bf16)v;
                } else {
                    v += bias[cc] + Cf[idx];
                    Cf[idx] = v;
                }
            }
}

// ---------------------------------------------------------------------------
// Transpose V
// ---------------------------------------------------------------------------
__global__ __launch_bounds__(256) void transpose_v(const bf16* __restrict__ qkv,
                                                   bf16* __restrict__ vt) {
    __shared__ bf16 t[64][65];
    const int bh = blockIdx.y, ct = blockIdx.x;
    const int b = bh >> 4, a = bh & 15;
    for (int idx = threadIdx.x; idx < 4096; idx += 256) {
        int c = idx >> 6, h = idx & 63;
        t[h][c] = qkv[(size_t)(b * 2048 + ct * 64 + c) * 3072 + 2048 + a * 64 + h];
    }
    __syncthreads();
    for (int idx = threadIdx.x; idx < 4096; idx += 256) {
        int h = idx >> 6, c = idx & 63;
        vt[(size_t)(bh * 64 + h) * 2048 + ct * 64 + c] = t[h][c];
    }
}

// ---------------------------------------------------------------------------
// Attention pass 1: l_c = sum_{C<=c} exp(S/8). Stores mp2[c] = log2(l_c).
// 3-buffer Qt pipeline, swizzled tiles.
// ---------------------------------------------------------------------------
__global__ __launch_bounds__(256) void attn_stats(const bf16* __restrict__ qkv,
                                                  float* __restrict__ mp2) {
    __shared__ __align__(16) bf16 Kt[64 * 64];
    __shared__ __align__(16) bf16 Qt[3][64 * 64];
    const int xx = blockIdx.x;
    const int ct = (xx & 1) ? (31 - (xx >> 1)) : (xx >> 1);
    const int bh = blockIdx.y;
    const int b = bh >> 4, a = bh & 15;
    const int tid = threadIdx.x, wave = tid >> 6, lane = tid & 63;
    const int col = lane & 15, quad = lane >> 4;
    const bf16* base = qkv + (size_t)b * 2048 * 3072;

    stage64s(base + (size_t)ct * 64 * 3072 + 1024 + a * 64, 3072, Kt, wave, lane);
    stage64s(base + a * 64, 3072, Qt[0], wave, lane);
    if (ct >= 1) stage64s(base + (size_t)1 * 64 * 3072 + a * 64, 3072, Qt[1], wave, lane);

    float lrun[4] = {0.f, 0.f, 0.f, 0.f};
    bf16x8 a0, a1;

    for (int Ct = 0; Ct <= ct; ++Ct) {
        if (Ct < ct) asm volatile("s_waitcnt vmcnt(2)" ::: "memory");
        else         asm volatile("s_waitcnt vmcnt(0)" ::: "memory");
        __builtin_amdgcn_s_barrier();
        if (Ct + 2 <= ct)
            stage64s(base + (size_t)(Ct + 2) * 64 * 3072 + a * 64, 3072,
                     Qt[(Ct + 2) % 3], wave, lane);
        if (Ct == 0) {
            a0 = rd64(Kt, wave * 16 + col, quad);
            a1 = rd64(Kt, wave * 16 + col, quad + 4);
        }
        const bf16* q = Qt[Ct % 3];
#pragma unroll
        for (int nt = 0; nt < 4; ++nt) {
            bf16x8 b0 = rd64(q, nt * 16 + col, quad);
            bf16x8 b1 = rd64(q, nt * 16 + col, quad + 4);
            floatx4 sacc = (floatx4){0.f, 0.f, 0.f, 0.f};
            sacc = MFMA16(a0, b0, sacc);
            sacc = MFMA16(a1, b1, sacc);
#pragma unroll
            for (int r = 0; r < 4; ++r) {
                float e = __builtin_amdgcn_exp2f(sacc[r] * K2);
                if (Ct == ct && (nt * 16 + col) > (wave * 16 + quad * 4 + r)) e = 0.f;
                lrun[r] += e;
            }
        }
    }
#pragma unroll
    for (int r = 0; r < 4; ++r) {
        float t = lrun[r];
        t += __shfl_xor(t, 1);
        t += __shfl_xor(t, 2);
        t += __shfl_xor(t, 4);
        t += __shfl_xor(t, 8);
        lrun[r] = t;
    }
    if (col == 0) {
#pragma unroll
        for (int r = 0; r < 4; ++r) {
            int c = ct * 64 + wave * 16 + quad * 4 + r;
            mp2[(size_t)bh * 2048 + c] = __builtin_amdgcn_logf(lrun[r]);
        }
    }
}

// ---------------------------------------------------------------------------
// Attention pass 2: z[C][h] = sum_{c>=C} P[c][C]*v[c][h],
// P = exp2(S*K2 - mp2[c]). 3-buffer K/V pipeline; mp stats pre-staged to LDS
// (per-lane source address: DMA reads g+lane*16, writes lds+lane*16).
// ---------------------------------------------------------------------------
__global__ __launch_bounds__(256) void attn_av(const bf16* __restrict__ qkv,
                                               const bf16* __restrict__ vt,
                                               const float* __restrict__ mp2,
                                               bf16* __restrict__ zb) {
    __shared__ __align__(16) bf16 Qt[64 * 64];
    __shared__ __align__(16) bf16 Kt[3][64 * 64];
    __shared__ __align__(16) bf16 Vt[3][64 * 64];
    __shared__ __align__(16) bf16 Pt[64 * 72];
    __shared__ __align__(16) float mpS[2048];
    const int xx = blockIdx.x;
    const int Ctile = (xx & 1) ? (31 - (xx >> 1)) : (xx >> 1);
    const int bh = blockIdx.y;
    const int b = bh >> 4, a = bh & 15;
    const int tid = threadIdx.x, wave = tid >> 6, lane = tid & 63;
    const int col = lane & 15, quad = lane >> 4;
    const bf16* base = qkv + (size_t)b * 2048 * 3072;
    const float* mpb = mp2 + (size_t)bh * 2048;
    const int niter = 32 - Ctile;

    stage64s(base + (size_t)Ctile * 64 * 3072 + a * 64, 3072, Qt, wave, lane);
    {   // stage mp[Ctile*64 .. 2048) -> mpS[0 ..); 1024 B per wave-instr
        int nb = niter * 256;  // bytes
#pragma unroll
        for (int i = 0; i < 2; ++i) {
            int off = (i * 4 + wave) * 1024;  // wave-uniform
            if (off < nb)
                async16((const char*)(mpb + Ctile * 64) + off + lane * 16,  // per-lane!
                        (char*)mpS + off);
        }
    }
    stage64s(base + (size_t)Ctile * 64 * 3072 + 1024 + a * 64, 3072, Kt[0], wave, lane);
    stage64s(vt + (size_t)bh * 64 * 2048 + Ctile * 64, 2048, Vt[0], wave, lane);
    if (niter > 1) {
        stage64s(base + (size_t)(Ctile + 1) * 64 * 3072 + 1024 + a * 64, 3072, Kt[1], wave, lane);
        stage64s(vt + (size_t)bh * 64 * 2048 + (Ctile + 1) * 64, 2048, Vt[1], wave, lane);
    }

    floatx4 zacc[4];
#pragma unroll
    for (int mi = 0; mi < 4; ++mi) zacc[mi] = (floatx4){0.f, 0.f, 0.f, 0.f};
    bf16x8 qf0[4], qf1[4];

    for (int i = 0; i < niter; ++i) {
        const int ct = Ctile + i;
        // wait: KV(i) (+Qt/mp on i=0) done; KV(i+1)'s 4 loads stay in flight
        if (i + 1 < niter) asm volatile("s_waitcnt vmcnt(4)" ::: "memory");
        else               asm volatile("s_waitcnt vmcnt(0)" ::: "memory");
        __builtin_amdgcn_s_barrier();
        if (i + 2 < niter) {
            stage64s(base + (size_t)(ct + 2) * 64 * 3072 + 1024 + a * 64, 3072,
                     Kt[(i + 2) % 3], wave, lane);
            stage64s(vt + (size_t)bh * 64 * 2048 + (ct + 2) * 64, 2048,
                     Vt[(i + 2) % 3], wave, lane);
        }
        if (i == 0) {
#pragma unroll
            for (int nt = 0; nt < 4; ++nt) {
                qf0[nt] = rd64(Qt, nt * 16 + col, quad);
                qf1[nt] = rd64(Qt, nt * 16 + col, quad + 4);
            }
        }
        const bf16* kt = Kt[i % 3];
        const bf16* vts = Vt[i % 3];
        bf16x8 a0 = rd64(kt, wave * 16 + col, quad);
        bf16x8 a1 = rd64(kt, wave * 16 + col, quad + 4);
        float4 mpv = *(const float4*)&mpS[i * 64 + wave * 16 + quad * 4];
        const float mpl[4] = {mpv.x, mpv.y, mpv.z, mpv.w};

#pragma unroll
        for (int nt = 0; nt < 4; ++nt) {
            floatx4 sacc = (floatx4){0.f, 0.f, 0.f, 0.f};
            sacc = MFMA16(a0, qf0[nt], sacc);
            sacc = MFMA16(a1, qf1[nt], sacc);
            bf16x4 pv;
#pragma unroll
            for (int r = 0; r < 4; ++r) {
                float p;
                if (ct == Ctile && (nt * 16 + col) > (wave * 16 + quad * 4 + r))
                    p = 0.f;
                else
                    p = __builtin_amdgcn_exp2f(sacc[r] * K2 - mpl[r]);
                pv[r] = (bf16)p;
            }
            *(bf16x4*)&Pt[(nt * 16 + col) * 72 + wave * 16 + quad * 4] = pv;
        }
        // Pt visible; K/V DMA for ct+2 stays in flight
        asm volatile("s_waitcnt lgkmcnt(0)" ::: "memory");
        __builtin_amdgcn_s_barrier();

        bf16x8 v0 = rd64(vts, wave * 16 + col, quad);
        bf16x8 v1 = rd64(vts, wave * 16 + col, quad + 4);
#pragma unroll
        for (int mi = 0; mi < 4; ++mi) {
            bf16x8 p0 = *(const bf16x8*)&Pt[(mi * 16 + col) * 72 + quad * 8];
            bf16x8 p1 = *(const bf16x8*)&Pt[(mi * 16 + col) * 72 + 32 + quad * 8];
            zacc[mi] = MFMA16(p0, v0, zacc[mi]);
            zacc[mi] = MFMA16(p1, v1, zacc[mi]);
        }
    }
#pragma unroll
    for (int mi = 0; mi < 4; ++mi)
#pragma unroll
        for (int r = 0; r < 4; ++r) {
            int Cg = Ctile * 64 + mi * 16 + quad * 4 + r;
            zb[(size_t)(b * 2048 + Cg) * 1024 + a * 64 + wave * 16 + col] =
                (bf16)zacc[mi][r];
        }
}

// ---------------------------------------------------------------------------
// Host launcher
// ---------------------------------------------------------------------------
extern "C" void kernel_launch(void* const* d_in, const int* in_sizes, int n_in,
                              void* d_out, int out_size, void* d_ws, size_t ws_size,
                              hipStream_t stream) {
    (void)in_sizes; (void)n_in; (void)out_size; (void)ws_size;
    const float* x    = (const float*)d_in[0];
    const float* WK   = (const float*)d_in[1];
    const float* WQ   = (const float*)d_in[2];
    const float* WV   = (const float*)d_in[3];
    const float* WO   = (const float*)d_in[4];
    const float* Win  = (const float*)d_in[5];
    const float* bin  = (const float*)d_in[6];
    const float* Wout = (const float*)d_in[7];
    const float* bout = (const float*)d_in[8];
    float* out = (float*)d_out;

    char* ws = (char*)d_ws;
    bf16*  xb   = (bf16*)(ws + 0);          //  8 MB
    bf16*  wqkv = (bf16*)(ws + 8388608);    //  6 MB
    bf16*  wo   = (bf16*)(ws + 14680064);   //  2 MB
    bf16*  win  = (bf16*)(ws + 16777216);   //  8 MB
    bf16*  wout = (bf16*)(ws + 25165824);   //  8 MB
    bf16*  qkvb = (bf16*)(ws + 33554432);   // 24 MB
    bf16*  vtb  = (bf16*)(ws + 58720256);   //  8 MB
    float* mst  = (float*)(ws + 67108864);  // 256 KB (mp2)
    bf16*  zbuf = (bf16*)(ws + 67633152);   //  8 MB
    bf16*  xmid = (bf16*)(ws + 76021760);   //  8 MB
    bf16*  hbuf = (bf16*)(ws + 84410368);   // 32 MB

    cvt_all<<<16384, 256, 0, stream>>>(x, WQ, WK, WV, WO, Win, Wout,
                                       xb, wqkv, wo, win, wout);

    gemm_pipe<0, 128><<<dim3(24, 32), 256, 0, stream>>>(xb, 1024, wqkv, 1024, 1024,
                                                        nullptr, qkvb, 3072, nullptr, nullptr);
    transpose_v<<<dim3(32, 32), 256, 0, stream>>>(qkvb, vtb);
    attn_stats<<<dim3(32, 32), 256, 0, stream>>>(qkvb, mst);
    attn_av<<<dim3(32, 32), 256, 0, stream>>>(qkvb, vtb, mst, zbuf);
    gemm_pipe<1, 64><<<dim3(16, 32), 256, 0, stream>>>(zbuf, 1024, wo, 1024, 1024,
                                                       out, xmid, 1024, nullptr, x);
    gemm_pipe<2, 128><<<dim3(32, 32), 256, 0, stream>>>(xmid, 1024, win, 1024, 1024,
                                                        nullptr, hbuf, 4096, bin, nullptr);
    gemm_pipe<3, 64><<<dim3(16, 32), 256, 0, stream>>>(hbuf, 4096, wout, 4096, 4096,
                                                       out, nullptr, 1024, bout, nullptr);
}